// Round 9
// baseline (1450.872 us; speedup 1.0000x reference)
//
#include <hip/hip_runtime.h>
#include <stdint.h>

#define T_STEPS 256
#define BATCH   256
#define OBS     128
#define HID     256
#define HSZ     512
#define NG      16          // batch groups
#define RPG     16          // batch rows per group
#define NSLICES 16          // h-col slices per group
#define HCS     32          // h-cols per slice
#define RING_SLOT_W 65536   // u32 words per ring slot: 256 rows x 256 word-cols

typedef __attribute__((ext_vector_type(8))) short short8;
typedef __attribute__((ext_vector_type(4))) float f32x4;
typedef __attribute__((ext_vector_type(4))) int   i32x4;

__device__ __forceinline__ unsigned short f2bf(float x) {
    union { float f; uint32_t u; } v; v.f = x;
    uint32_t r = v.u + 0x7FFF + ((v.u >> 16) & 1);
    return (unsigned short)(r >> 16);
}
__device__ __forceinline__ float sigmoidf_(float x) { return 1.f / (1.f + __expf(-x)); }
__device__ __forceinline__ float tanhf_(float x)    { return 1.f - 2.f / (1.f + __expf(2.f * x)); }

// 4 coherent (L1/L2-bypass -> L3) 16B loads; "=&v" early-clobber mandatory.
#define GLD4(d0, d1, d2, d3, p, O0, O1, O2, O3)                                 \
    asm volatile("global_load_dwordx4 %0, %4, off offset:" #O0 " sc0 sc1\n\t"   \
                 "global_load_dwordx4 %1, %4, off offset:" #O1 " sc0 sc1\n\t"   \
                 "global_load_dwordx4 %2, %4, off offset:" #O2 " sc0 sc1\n\t"   \
                 "global_load_dwordx4 %3, %4, off offset:" #O3 " sc0 sc1"       \
                 : "=&v"(d0), "=&v"(d1), "=&v"(d2), "=&v"(d3) : "v"(p))

// ---------------- Encoder: feats = gelu(x @ W_enc + b_enc), bf16 out ----------------
__global__ __launch_bounds__(256) void enc_kernel(
    const float* __restrict__ x, const float* __restrict__ W_enc,
    const float* __restrict__ b_enc, unsigned short* __restrict__ feats) {
    __shared__ unsigned short wlds[HID * OBS];   // [n=256][k=128] bf16 swizzled, 64KB
    int tid = threadIdx.x;
    for (int idx = tid; idx < OBS * HID; idx += 256) {
        int k = idx >> 8, n = idx & 255;
        int byte = ((n * OBS + k) * 2) ^ ((n & 7) << 4);
        *(unsigned short*)((char*)wlds + byte) = f2bf(W_enc[k * HID + n]);
    }
    __syncthreads();
    int wave = tid >> 6, lane = tid & 63;
    long m0 = (long)blockIdx.x * 64 + wave * 16;
    int arow = lane & 15, kq = lane >> 4;
    f32x4 acc[16];
    f32x4 z4 = {0.f, 0.f, 0.f, 0.f};
#pragma unroll
    for (int i = 0; i < 16; i++) acc[i] = z4;
#pragma unroll
    for (int kk = 0; kk < OBS; kk += 32) {
        const float* ap = x + (m0 + arow) * OBS + kk + kq * 8;
        float4 a0 = *(const float4*)ap;
        float4 a1 = *(const float4*)(ap + 4);
        short8 af;
        af[0] = (short)f2bf(a0.x); af[1] = (short)f2bf(a0.y);
        af[2] = (short)f2bf(a0.z); af[3] = (short)f2bf(a0.w);
        af[4] = (short)f2bf(a1.x); af[5] = (short)f2bf(a1.y);
        af[6] = (short)f2bf(a1.z); af[7] = (short)f2bf(a1.w);
#pragma unroll
        for (int nt = 0; nt < 16; nt++) {
            int n = nt * 16 + arow;
            int byte = ((n * OBS + kk + kq * 8) * 2) ^ ((n & 7) << 4);
            short8 bf = *(const short8*)((char*)wlds + byte);
            acc[nt] = __builtin_amdgcn_mfma_f32_16x16x32_bf16(af, bf, acc[nt], 0, 0, 0);
        }
    }
#pragma unroll
    for (int nt = 0; nt < 16; nt++) {
        int col = nt * 16 + (lane & 15);
        float bias = b_enc[col];
#pragma unroll
        for (int j = 0; j < 4; j++) {
            long row = m0 + kq * 4 + j;
            float z = acc[nt][j] + bias;
            float zc = 0.79788456f * (z + 0.044715f * z * z * z);
            float g = 0.5f * z * (1.f + tanhf_(zc));
            feats[row * HID + col] = f2bf(g);
        }
    }
}

// ---------------- Prep: Wi fragments, per-lane layout ----------------
__global__ __launch_bounds__(256) void prep_wi(
    const float* __restrict__ Wi, unsigned short* __restrict__ Wipk) {
    int t = blockIdx.x * 256 + threadIdx.x;        // 65536 threads
    int f = t & 15, l = (t >> 4) & 63, w = (t >> 10) & 3, s = t >> 12;
    int ct = f >> 3, i = f & 7;
    int n = w * 32 + ct * 16 + (l & 15);
    int colg = (n & 3) * HSZ + s * HCS + (n >> 2);
    int kbase = i * 32 + (l >> 4) * 8;
    short8 v;
#pragma unroll
    for (int j = 0; j < 8; j++) v[j] = (short)f2bf(Wi[(kbase + j) * 2048 + colg]);
    *(short8*)(Wipk + (long)t * 8) = v;
}

// ---------------- Prep: Wh fragments for the b0 half (cols wc..wc+15 per wave) ----------------
__global__ __launch_bounds__(256) void prep_wh(
    const float* __restrict__ Wh, unsigned short* __restrict__ Whpk) {
    int t = blockIdx.x * 256 + threadIdx.x;        // 65536 threads
    int l = t & 63, i = (t >> 6) & 15, w = (t >> 10) & 3, s = t >> 12;
    int n = w * 32 + (l & 15);
    int colg = (n & 3) * HSZ + s * HCS + (n >> 2);
    int kbase = i * 32 + (l >> 4) * 8;
    short8 v;
#pragma unroll
    for (int j = 0; j < 8; j++) v[j] = (short)f2bf(Wh[(kbase + j) * 2048 + colg]);
    *(short8*)(Whpk + (long)t * 8) = v;            // [((s*4+w)*16+i)*64+l]
}

// ---------------- Persistent LSTM scan (sentinel data-poll, 1 barrier/step) ----------------
// 256 WGs = 16 groups x 16 slices; LDS 96KB -> 1 WG/CU, all resident.
__global__ __launch_bounds__(256, 1) void scan_kernel(
    const float* __restrict__ b_lstm, const unsigned short* __restrict__ feats,
    const unsigned short* __restrict__ Wipk, const unsigned short* __restrict__ Whpk,
    const float* __restrict__ Wh, uint32_t* __restrict__ ring,
    uint32_t* __restrict__ hs32) {
    __shared__ unsigned short whs[64 * HSZ];      // b1-half Wh [n'=64][k=512] swizzled, 64KB
    __shared__ unsigned short hst[2 * RPG * HSZ]; // h stage dbuf [2][16][512] swizzled, 32KB
    const int tid = threadIdx.x;
    const int g = blockIdx.x & 15;
    const int slice = blockIdx.x >> 4;
    const int rowg = g * RPG;
    const int wave = tid >> 6, lane = tid & 63;
    const int arow = lane & 15, kq = lane >> 4;

    // Stage b1-half of Wh slice: LDS n' = wave*16+ar <-> global col n1 = wave*32+16+ar
    for (int idx = tid; idx < 64 * HSZ; idx += 256) {
        int np = idx & 63, k = idx >> 6;
        int n1 = (np >> 4) * 32 + 16 + (np & 15);
        int colg = (n1 & 3) * HSZ + slice * HCS + (n1 >> 2);
        int byte = ((np * HSZ + k) * 2) ^ ((np & 7) << 4);
        *(unsigned short*)((char*)whs + byte) = f2bf(Wh[k * 2048 + colg]);
    }
    // Wi fragments (both halves) and Wh b0-half fragments -> registers
    short8 wif0[8], wif1[8], whb[16];
    {
        const short8* wp = (const short8*)Wipk + ((slice * 4 + wave) * 64 + lane) * 16;
#pragma unroll
        for (int i = 0; i < 8; i++) { wif0[i] = wp[i]; wif1[i] = wp[8 + i]; }
        const short8* hp8 = (const short8*)Whpk;
#pragma unroll
        for (int i = 0; i < 16; i++)
            whb[i] = hp8[((slice * 4 + wave) * 16 + i) * 64 + lane];
    }
    // per-lane gate ownership after transpose: row kq*4+(arow&3), hcols hcol0, hcol0+4
    const int a_ = arow >> 2;
    const int hcol0 = slice * HCS + wave * 8 + a_;
    float bl0[4], bl1[4];
#pragma unroll
    for (int q = 0; q < 4; q++) {
        bl0[q] = b_lstm[q * HSZ + hcol0];
        bl1[q] = b_lstm[q * HSZ + hcol0 + 4];
    }
    const int row = kq * 4 + (arow & 3);
    int colw = slice * 16 + wave * 4 + ((a_ & 1) ? 2 + (a_ >> 1) : (a_ >> 1));
    float c0 = 0.f, c1 = 0.f;
    const int srow = tid >> 4, sc64 = tid & 15;   // poll/stage ownership: 64B per thread
    const int sw = (srow & 7) << 4;
    // feats prefetch for t=0
    short8 ff[8];
    {
        const char* fb = (const char*)feats + ((long)(rowg + arow)) * (HID * 2) + kq * 16;
#pragma unroll
        for (int i = 0; i < 8; i++) ff[i] = *(const short8*)(fb + i * 64);
    }
    f32x4 z4 = {0.f, 0.f, 0.f, 0.f};
    __syncthreads();

    for (int t = 0; t < T_STEPS; ++t) {
        // 1. x-gates: pure register MFMA (ff prefetched, wif in regs)
        f32x4 acc0 = z4, acc1 = z4;
#pragma unroll
        for (int i = 0; i < 8; i++) {
            acc0 = __builtin_amdgcn_mfma_f32_16x16x32_bf16(ff[i], wif0[i], acc0, 0, 0, 0);
            acc1 = __builtin_amdgcn_mfma_f32_16x16x32_bf16(ff[i], wif1[i], acc1, 0, 0, 0);
        }
        // 2. prefetch feats for t+1 (overlaps poll + MFMA phase)
        {
            int tn = (t + 1 < T_STEPS) ? t + 1 : t;
            const char* fb = (const char*)feats
                           + ((long)tn * BATCH + rowg + arow) * (HID * 2) + kq * 16;
#pragma unroll
            for (int i = 0; i < 8; i++) ff[i] = *(const short8*)(fb + i * 64);
        }
        __builtin_amdgcn_sched_barrier(0);
        // 3. poll own 64B chunk of h[t-1] (data IS the signal), stage into hst
        if (t > 0) {
            const char* pb = (const char*)ring + ((t - 1) & 3) * (RING_SLOT_W * 4)
                           + (rowg + srow) * 1024 + sc64 * 64;
            i32x4 S0, S1, S2, S3;
            while (true) {
                GLD4(S0, S1, S2, S3, pb, 0, 16, 32, 48);
                asm volatile("s_waitcnt vmcnt(0)" ::: "memory");
                bool ok = S0[0] != -1 && S0[1] != -1 && S0[2] != -1 && S0[3] != -1
                       && S1[0] != -1 && S1[1] != -1 && S1[2] != -1 && S1[3] != -1
                       && S2[0] != -1 && S2[1] != -1 && S2[2] != -1 && S2[3] != -1
                       && S3[0] != -1 && S3[1] != -1 && S3[2] != -1 && S3[3] != -1;
                if (ok) break;
                __builtin_amdgcn_s_sleep(1);
            }
            __builtin_amdgcn_sched_barrier(0);
            char* hb = (char*)hst + (t & 1) * 16384;
            int sb = srow * 1024 + sc64 * 64;
            *(i32x4*)(hb + ((sb +  0) ^ sw)) = S0;
            *(i32x4*)(hb + ((sb + 16) ^ sw)) = S1;
            *(i32x4*)(hb + ((sb + 32) ^ sw)) = S2;
            *(i32x4*)(hb + ((sb + 48) ^ sw)) = S3;
        }
        __syncthreads();
        // 5. recurrent MFMAs: A from staged h (LDS), B0 from regs, B1 from LDS
        if (t > 0) {
            const char* hb = (const char*)hst + (t & 1) * 16384;
            const int np = wave * 16 + arow;
#pragma unroll
            for (int i = 0; i < 16; i++) {
                short8 ah = *(const short8*)(hb
                              + ((arow * 1024 + i * 64 + kq * 16) ^ ((arow & 7) << 4)));
                short8 b1 = *(const short8*)((char*)whs
                              + ((np * 1024 + i * 64 + kq * 16) ^ ((np & 7) << 4)));
                acc0 = __builtin_amdgcn_mfma_f32_16x16x32_bf16(ah, whb[i], acc0, 0, 0, 0);
                acc1 = __builtin_amdgcn_mfma_f32_16x16x32_bf16(ah, b1, acc1, 0, 0, 0);
            }
        }
        // 6. 4x4 in-cluster transpose (lanes arow&3, regs j) -> lane holds i,f,g,o
        float C0, C1, C2, C3, D0, D1, D2, D3;
        {
            float s0 = __shfl_xor(acc0[0], 1), s1 = __shfl_xor(acc0[1], 1);
            float s2 = __shfl_xor(acc0[2], 1), s3 = __shfl_xor(acc0[3], 1);
            bool o1 = arow & 1;
            float b0_ = o1 ? s1 : acc0[0], b1_ = o1 ? acc0[1] : s0;
            float b2_ = o1 ? s3 : acc0[2], b3_ = o1 ? acc0[3] : s2;
            float r0 = __shfl_xor(b0_, 2), r1 = __shfl_xor(b1_, 2);
            float r2 = __shfl_xor(b2_, 2), r3 = __shfl_xor(b3_, 2);
            bool o2 = arow & 2;
            C0 = o2 ? r2 : b0_; C1 = o2 ? r3 : b1_;
            C2 = o2 ? b2_ : r0; C3 = o2 ? b3_ : r1;
            s0 = __shfl_xor(acc1[0], 1); s1 = __shfl_xor(acc1[1], 1);
            s2 = __shfl_xor(acc1[2], 1); s3 = __shfl_xor(acc1[3], 1);
            b0_ = o1 ? s1 : acc1[0]; b1_ = o1 ? acc1[1] : s0;
            b2_ = o1 ? s3 : acc1[2]; b3_ = o1 ? acc1[3] : s2;
            r0 = __shfl_xor(b0_, 2); r1 = __shfl_xor(b1_, 2);
            r2 = __shfl_xor(b2_, 2); r3 = __shfl_xor(b3_, 2);
            D0 = o2 ? r2 : b0_; D1 = o2 ? r3 : b1_;
            D2 = o2 ? b2_ : r0; D3 = o2 ? b3_ : r1;
        }
        // 7. gates (i,f,g,o) and cell update; pack hcol pairs via shfl_xor(4)
        c0 = sigmoidf_(C1 + bl0[1]) * c0 + sigmoidf_(C0 + bl0[0]) * tanhf_(C2 + bl0[2]);
        c1 = sigmoidf_(D1 + bl1[1]) * c1 + sigmoidf_(D0 + bl1[0]) * tanhf_(D2 + bl1[2]);
        float h0 = sigmoidf_(C3 + bl0[3]) * tanhf_(c0);
        float h1 = sigmoidf_(D3 + bl1[3]) * tanhf_(c1);
        uint32_t hu0 = f2bf(h0), hu1 = f2bf(h1);
        uint32_t p0 = (uint32_t)__shfl_xor((int)hu0, 4);
        uint32_t p1 = (uint32_t)__shfl_xor((int)hu1, 4);
        uint32_t word = (a_ & 1) ? (p1 | (hu1 << 16)) : (hu0 | (p0 << 16));
        uint32_t* wp = ring + (t & 3) * RING_SLOT_W + (rowg + row) * 256 + colw;
        asm volatile("global_store_dword %0, %1, off sc0 sc1" :: "v"(wp), "v"(word) : "memory");
        hs32[((long)t * BATCH + rowg + row) * 256 + colw] = word;   // for heads (cached)
        if (t >= 2) {   // re-sentinel the word this thread wrote at t-2 (consumed at t-1)
            uint32_t* rp = ring + ((t - 2) & 3) * RING_SLOT_W + (rowg + row) * 256 + colw;
            uint32_t sen = 0xFFFFFFFFu;
            asm volatile("global_store_dword %0, %1, off sc0 sc1" :: "v"(rp), "v"(sen) : "memory");
        }
    }
}

// ---------------- Heads: mu/sigma/value from hs (separate dispatch) ----------------
__global__ __launch_bounds__(256) void heads_kernel(
    const unsigned short* __restrict__ hs, const float* __restrict__ W_mu,
    const float* __restrict__ b_mu, const float* __restrict__ log_std,
    const float* __restrict__ W_v, const float* __restrict__ b_v,
    float* __restrict__ mu_out, float* __restrict__ sig_out,
    float* __restrict__ val_out) {
    __shared__ unsigned short wlds[32 * HSZ];     // [n=32][k=512]: 0-15 mu, 16 v, rest 0
    int tid = threadIdx.x;
    for (int idx = tid; idx < 32 * HSZ; idx += 256) {
        int n = idx & 31, k = idx >> 5;
        float w = 0.f;
        if (n < 16) w = W_mu[k * 16 + n];
        else if (n == 16) w = W_v[k];
        int byte = ((n * HSZ + k) * 2) ^ ((n & 7) << 4);
        *(unsigned short*)((char*)wlds + byte) = f2bf(w);
    }
    __syncthreads();
    int wave = tid >> 6, lane = tid & 63;
    long m0 = (long)blockIdx.x * 64 + wave * 16;
    int arow = lane & 15, kq = lane >> 4;
    f32x4 acc0 = {0.f, 0.f, 0.f, 0.f}, acc1 = {0.f, 0.f, 0.f, 0.f};
    const unsigned short* hr = hs + (m0 + arow) * HSZ + kq * 8;
#pragma unroll
    for (int kk = 0; kk < HSZ; kk += 32) {
        short8 af = *(const short8*)(hr + kk);
        int n0 = arow;
        int b0 = ((n0 * HSZ + kk + kq * 8) * 2) ^ ((n0 & 7) << 4);
        short8 bf0 = *(const short8*)((char*)wlds + b0);
        acc0 = __builtin_amdgcn_mfma_f32_16x16x32_bf16(af, bf0, acc0, 0, 0, 0);
        int n1 = 16 + arow;
        int b1 = ((n1 * HSZ + kk + kq * 8) * 2) ^ ((n1 & 7) << 4);
        short8 bf1 = *(const short8*)((char*)wlds + b1);
        acc1 = __builtin_amdgcn_mfma_f32_16x16x32_bf16(af, bf1, acc1, 0, 0, 0);
    }
    int col = lane & 15;
    float bm = b_mu[col];
    float sg = __expf(log_std[col]);
#pragma unroll
    for (int j = 0; j < 4; j++) {
        long row = m0 + kq * 4 + j;
        mu_out[row * 16 + col]  = acc0[j] + bm;
        sig_out[row * 16 + col] = sg;
    }
    if (col == 0) {
        float bv = b_v[0];
#pragma unroll
        for (int j = 0; j < 4; j++) {
            long row = m0 + kq * 4 + j;
            val_out[row] = acc1[j] + bv;
        }
    }
}

extern "C" void kernel_launch(void* const* d_in, const int* in_sizes, int n_in,
                              void* d_out, int out_size, void* d_ws, size_t ws_size,
                              hipStream_t stream) {
    const float* x      = (const float*)d_in[0];
    const float* W_enc  = (const float*)d_in[1];
    const float* b_enc  = (const float*)d_in[2];
    const float* Wi     = (const float*)d_in[3];
    const float* Wh     = (const float*)d_in[4];
    const float* b_lstm = (const float*)d_in[5];
    const float* W_mu   = (const float*)d_in[6];
    const float* b_mu   = (const float*)d_in[7];
    const float* lstd   = (const float*)d_in[8];
    const float* W_v    = (const float*)d_in[9];
    const float* b_v    = (const float*)d_in[10];

    char* ws = (char*)d_ws;
    uint32_t*       ring  = (uint32_t*)ws;                            // 1MB ring (4 slots)
    unsigned short* Wipk  = (unsigned short*)(ws + (1 << 20));        // 1MB packed Wi
    unsigned short* Whpk  = (unsigned short*)(ws + (2 << 20));        // 1MB packed Wh b0-half
    unsigned short* feats = (unsigned short*)(ws + (3 << 20));        // 33.6MB bf16
    unsigned short* hs    = (unsigned short*)(ws + (3 << 20) + 33554432); // 67.1MB
    // total ws use: ~104MB

    float* mu_out  = (float*)d_out;                 // (T*B,16) f32
    float* sig_out = mu_out + 1048576;              // (T*B,16) f32
    float* val_out = mu_out + 2097152;              // (T*B,)   f32

    hipMemsetAsync(ring, 0xFF, 4 * RING_SLOT_W * sizeof(uint32_t), stream);  // sentinels
    prep_wi<<<dim3(256), dim3(256), 0, stream>>>(Wi, Wipk);
    prep_wh<<<dim3(256), dim3(256), 0, stream>>>(Wh, Whpk);
    enc_kernel<<<dim3(1024), dim3(256), 0, stream>>>(x, W_enc, b_enc, feats);
    scan_kernel<<<dim3(256), dim3(256), 0, stream>>>(b_lstm, feats, Wipk, Whpk, Wh,
                                                     ring, (uint32_t*)hs);
    heads_kernel<<<dim3(1024), dim3(256), 0, stream>>>(hs, W_mu, b_mu, lstd, W_v, b_v,
                                                       mu_out, sig_out, val_out);
}

// Round 10
// 1328.992 us; speedup vs baseline: 1.0917x; 1.0917x over previous
//
#include <hip/hip_runtime.h>
#include <stdint.h>

#define T_STEPS 256
#define BATCH   256
#define OBS     128
#define HID     256
#define HSZ     512
#define NG      16          // batch groups
#define RPG     16          // batch rows per group
#define NSLICES 16          // h-col slices per group
#define HCS     32          // h-cols per slice
#define RING_SLOT_W 65536   // u32 words per ring slot: 256 rows x 256 word-cols

typedef __attribute__((ext_vector_type(8))) short short8;
typedef __attribute__((ext_vector_type(4))) float f32x4;
typedef __attribute__((ext_vector_type(4))) int   i32x4;

__device__ __forceinline__ unsigned short f2bf(float x) {
    union { float f; uint32_t u; } v; v.f = x;
    uint32_t r = v.u + 0x7FFF + ((v.u >> 16) & 1);
    return (unsigned short)(r >> 16);
}
__device__ __forceinline__ float sigmoidf_(float x) { return 1.f / (1.f + __expf(-x)); }
__device__ __forceinline__ float tanhf_(float x)    { return 1.f - 2.f / (1.f + __expf(2.f * x)); }

// 4 coherent (L1/L2-bypass -> L3) 16B loads; "=&v" early-clobber mandatory.
#define GLD4(d0, d1, d2, d3, p, O0, O1, O2, O3)                                 \
    asm volatile("global_load_dwordx4 %0, %4, off offset:" #O0 " sc0 sc1\n\t"   \
                 "global_load_dwordx4 %1, %4, off offset:" #O1 " sc0 sc1\n\t"   \
                 "global_load_dwordx4 %2, %4, off offset:" #O2 " sc0 sc1\n\t"   \
                 "global_load_dwordx4 %3, %4, off offset:" #O3 " sc0 sc1"       \
                 : "=&v"(d0), "=&v"(d1), "=&v"(d2), "=&v"(d3) : "v"(p))

// ---------------- Encoder: feats = gelu(x @ W_enc + b_enc), bf16 out ----------------
__global__ __launch_bounds__(256) void enc_kernel(
    const float* __restrict__ x, const float* __restrict__ W_enc,
    const float* __restrict__ b_enc, unsigned short* __restrict__ feats) {
    __shared__ unsigned short wlds[HID * OBS];   // [n=256][k=128] bf16 swizzled, 64KB
    int tid = threadIdx.x;
    for (int idx = tid; idx < OBS * HID; idx += 256) {
        int k = idx >> 8, n = idx & 255;
        int byte = ((n * OBS + k) * 2) ^ ((n & 7) << 4);
        *(unsigned short*)((char*)wlds + byte) = f2bf(W_enc[k * HID + n]);
    }
    __syncthreads();
    int wave = tid >> 6, lane = tid & 63;
    long m0 = (long)blockIdx.x * 64 + wave * 16;
    int arow = lane & 15, kq = lane >> 4;
    f32x4 acc[16];
    f32x4 z4 = {0.f, 0.f, 0.f, 0.f};
#pragma unroll
    for (int i = 0; i < 16; i++) acc[i] = z4;
#pragma unroll
    for (int kk = 0; kk < OBS; kk += 32) {
        const float* ap = x + (m0 + arow) * OBS + kk + kq * 8;
        float4 a0 = *(const float4*)ap;
        float4 a1 = *(const float4*)(ap + 4);
        short8 af;
        af[0] = (short)f2bf(a0.x); af[1] = (short)f2bf(a0.y);
        af[2] = (short)f2bf(a0.z); af[3] = (short)f2bf(a0.w);
        af[4] = (short)f2bf(a1.x); af[5] = (short)f2bf(a1.y);
        af[6] = (short)f2bf(a1.z); af[7] = (short)f2bf(a1.w);
#pragma unroll
        for (int nt = 0; nt < 16; nt++) {
            int n = nt * 16 + arow;
            int byte = ((n * OBS + kk + kq * 8) * 2) ^ ((n & 7) << 4);
            short8 bf = *(const short8*)((char*)wlds + byte);
            acc[nt] = __builtin_amdgcn_mfma_f32_16x16x32_bf16(af, bf, acc[nt], 0, 0, 0);
        }
    }
#pragma unroll
    for (int nt = 0; nt < 16; nt++) {
        int col = nt * 16 + (lane & 15);
        float bias = b_enc[col];
#pragma unroll
        for (int j = 0; j < 4; j++) {
            long row = m0 + kq * 4 + j;
            float z = acc[nt][j] + bias;
            float zc = 0.79788456f * (z + 0.044715f * z * z * z);
            float g = 0.5f * z * (1.f + tanhf_(zc));
            feats[row * HID + col] = f2bf(g);
        }
    }
}

// ---------------- Prep: Wi fragments, per-lane layout ----------------
__global__ __launch_bounds__(256) void prep_wi(
    const float* __restrict__ Wi, unsigned short* __restrict__ Wipk) {
    int t = blockIdx.x * 256 + threadIdx.x;        // 65536 threads
    int f = t & 15, l = (t >> 4) & 63, w = (t >> 10) & 3, s = t >> 12;
    int ct = f >> 3, i = f & 7;
    int n = w * 32 + ct * 16 + (l & 15);
    int colg = (n & 3) * HSZ + s * HCS + (n >> 2);
    int kbase = i * 32 + (l >> 4) * 8;
    short8 v;
#pragma unroll
    for (int j = 0; j < 8; j++) v[j] = (short)f2bf(Wi[(kbase + j) * 2048 + colg]);
    *(short8*)(Wipk + (long)t * 8) = v;
}

// ---------------- Prep: Wh fragments for the b0 half (cols wc..wc+15 per wave) ----------------
__global__ __launch_bounds__(256) void prep_wh(
    const float* __restrict__ Wh, unsigned short* __restrict__ Whpk) {
    int t = blockIdx.x * 256 + threadIdx.x;        // 65536 threads
    int l = t & 63, i = (t >> 6) & 15, w = (t >> 10) & 3, s = t >> 12;
    int n = w * 32 + (l & 15);
    int colg = (n & 3) * HSZ + s * HCS + (n >> 2);
    int kbase = i * 32 + (l >> 4) * 8;
    short8 v;
#pragma unroll
    for (int j = 0; j < 8; j++) v[j] = (short)f2bf(Wh[(kbase + j) * 2048 + colg]);
    *(short8*)(Whpk + (long)t * 8) = v;            // [((s*4+w)*16+i)*64+l]
}

// ---------------- Persistent LSTM scan (per-wave flags, 1 barrier/step) ----------------
// 256 WGs = 16 groups x 16 slices; LDS 96KB -> 1 WG/CU, all resident.
__global__ __launch_bounds__(256, 1) void scan_kernel(
    const float* __restrict__ b_lstm, const unsigned short* __restrict__ feats,
    const unsigned short* __restrict__ Wipk, const unsigned short* __restrict__ Whpk,
    const float* __restrict__ Wh, uint32_t* __restrict__ ring,
    uint32_t* __restrict__ flags, uint32_t* __restrict__ hs32) {
    __shared__ unsigned short whs[64 * HSZ];      // b1-half Wh [n'=64][k=512] swizzled, 64KB
    __shared__ unsigned short hst[2 * RPG * HSZ]; // h stage dbuf [2][16][512] swizzled, 32KB
    const int tid = threadIdx.x;
    const int g = blockIdx.x & 15;
    const int slice = blockIdx.x >> 4;
    const int rowg = g * RPG;
    const int wave = tid >> 6, lane = tid & 63;
    const int arow = lane & 15, kq = lane >> 4;

    // Stage b1-half of Wh slice: LDS n' = wave*16+ar <-> global col n1 = wave*32+16+ar
    for (int idx = tid; idx < 64 * HSZ; idx += 256) {
        int np = idx & 63, k = idx >> 6;
        int n1 = (np >> 4) * 32 + 16 + (np & 15);
        int colg = (n1 & 3) * HSZ + slice * HCS + (n1 >> 2);
        int byte = ((np * HSZ + k) * 2) ^ ((np & 7) << 4);
        *(unsigned short*)((char*)whs + byte) = f2bf(Wh[k * 2048 + colg]);
    }
    // Wi fragments (both halves) and Wh b0-half fragments -> registers
    short8 wif0[8], wif1[8], whb[16];
    {
        const short8* wp = (const short8*)Wipk + ((slice * 4 + wave) * 64 + lane) * 16;
#pragma unroll
        for (int i = 0; i < 8; i++) { wif0[i] = wp[i]; wif1[i] = wp[8 + i]; }
        const short8* hp8 = (const short8*)Whpk;
#pragma unroll
        for (int i = 0; i < 16; i++)
            whb[i] = hp8[((slice * 4 + wave) * 16 + i) * 64 + lane];
    }
    // per-lane gate ownership after transpose: row kq*4+(arow&3), hcols hcol0, hcol0+4
    const int a_ = arow >> 2;
    const int hcol0 = slice * HCS + wave * 8 + a_;
    float bl0[4], bl1[4];
#pragma unroll
    for (int q = 0; q < 4; q++) {
        bl0[q] = b_lstm[q * HSZ + hcol0];
        bl1[q] = b_lstm[q * HSZ + hcol0 + 4];
    }
    const int row = kq * 4 + (arow & 3);
    int colw = slice * 16 + wave * 4 + ((a_ & 1) ? 2 + (a_ >> 1) : (a_ >> 1));
    float c0 = 0.f, c1 = 0.f;
    const int srow = tid >> 4, sc64 = tid & 15;   // stage ownership: 64B per thread
    const int sw = (srow & 7) << 4;
    // feats prefetch for t=0
    short8 ff[8];
    {
        const char* fb = (const char*)feats + ((long)(rowg + arow)) * (HID * 2) + kq * 16;
#pragma unroll
        for (int i = 0; i < 8; i++) ff[i] = *(const short8*)(fb + i * 64);
    }
    f32x4 z4 = {0.f, 0.f, 0.f, 0.f};
    __syncthreads();

    for (int t = 0; t < T_STEPS; ++t) {
        // 1. x-gates: pure register MFMA (ff prefetched, wif in regs)
        f32x4 acc0 = z4, acc1 = z4;
#pragma unroll
        for (int i = 0; i < 8; i++) {
            acc0 = __builtin_amdgcn_mfma_f32_16x16x32_bf16(ff[i], wif0[i], acc0, 0, 0, 0);
            acc1 = __builtin_amdgcn_mfma_f32_16x16x32_bf16(ff[i], wif1[i], acc1, 0, 0, 0);
        }
        // 2. prefetch feats for t+1 (overlaps poll + MFMA phase)
        {
            int tn = (t + 1 < T_STEPS) ? t + 1 : t;
            const char* fb = (const char*)feats
                           + ((long)tn * BATCH + rowg + arow) * (HID * 2) + kq * 16;
#pragma unroll
            for (int i = 0; i < 8; i++) ff[i] = *(const short8*)(fb + i * 64);
        }
        __builtin_amdgcn_sched_barrier(0);
        // 3. poll 64 per-wave flags (all 4 waves; lane i polls flag i), then stage h
        if (t > 0) {
            const uint32_t* fp = flags + ((long)g * T_STEPS + t - 1) * 64 + lane;
            while (!__all(__hip_atomic_load(fp, __ATOMIC_RELAXED,
                                            __HIP_MEMORY_SCOPE_AGENT) != 0u)) {}
            __builtin_amdgcn_sched_barrier(0);
            const char* pb = (const char*)ring + ((t - 1) & 3) * (RING_SLOT_W * 4)
                           + (rowg + srow) * 1024 + sc64 * 64;
            i32x4 S0, S1, S2, S3;
            GLD4(S0, S1, S2, S3, pb, 0, 16, 32, 48);
            asm volatile("s_waitcnt vmcnt(0)" ::: "memory");
            __builtin_amdgcn_sched_barrier(0);
            char* hb = (char*)hst + (t & 1) * 16384;
            int sb = srow * 1024 + sc64 * 64;
            *(i32x4*)(hb + ((sb +  0) ^ sw)) = S0;
            *(i32x4*)(hb + ((sb + 16) ^ sw)) = S1;
            *(i32x4*)(hb + ((sb + 32) ^ sw)) = S2;
            *(i32x4*)(hb + ((sb + 48) ^ sw)) = S3;
        }
        __syncthreads();            // the ONLY barrier per step
        // 4. recurrent MFMAs: A from staged h (LDS), B0 from regs, B1 from LDS
        if (t > 0) {
            const char* hb = (const char*)hst + (t & 1) * 16384;
            const int np = wave * 16 + arow;
#pragma unroll
            for (int i = 0; i < 16; i++) {
                short8 ah = *(const short8*)(hb
                              + ((arow * 1024 + i * 64 + kq * 16) ^ ((arow & 7) << 4)));
                short8 b1 = *(const short8*)((char*)whs
                              + ((np * 1024 + i * 64 + kq * 16) ^ ((np & 7) << 4)));
                acc0 = __builtin_amdgcn_mfma_f32_16x16x32_bf16(ah, whb[i], acc0, 0, 0, 0);
                acc1 = __builtin_amdgcn_mfma_f32_16x16x32_bf16(ah, b1, acc1, 0, 0, 0);
            }
        }
        // 5. 4x4 in-cluster transpose (lanes arow&3, regs j) -> lane holds i,f,g,o
        float C0, C1, C2, C3, D0, D1, D2, D3;
        {
            float s0 = __shfl_xor(acc0[0], 1), s1 = __shfl_xor(acc0[1], 1);
            float s2 = __shfl_xor(acc0[2], 1), s3 = __shfl_xor(acc0[3], 1);
            bool o1 = arow & 1;
            float b0_ = o1 ? s1 : acc0[0], b1_ = o1 ? acc0[1] : s0;
            float b2_ = o1 ? s3 : acc0[2], b3_ = o1 ? acc0[3] : s2;
            float r0 = __shfl_xor(b0_, 2), r1 = __shfl_xor(b1_, 2);
            float r2 = __shfl_xor(b2_, 2), r3 = __shfl_xor(b3_, 2);
            bool o2 = arow & 2;
            C0 = o2 ? r2 : b0_; C1 = o2 ? r3 : b1_;
            C2 = o2 ? b2_ : r0; C3 = o2 ? b3_ : r1;
            s0 = __shfl_xor(acc1[0], 1); s1 = __shfl_xor(acc1[1], 1);
            s2 = __shfl_xor(acc1[2], 1); s3 = __shfl_xor(acc1[3], 1);
            b0_ = o1 ? s1 : acc1[0]; b1_ = o1 ? acc1[1] : s0;
            b2_ = o1 ? s3 : acc1[2]; b3_ = o1 ? acc1[3] : s2;
            r0 = __shfl_xor(b0_, 2); r1 = __shfl_xor(b1_, 2);
            r2 = __shfl_xor(b2_, 2); r3 = __shfl_xor(b3_, 2);
            D0 = o2 ? r2 : b0_; D1 = o2 ? r3 : b1_;
            D2 = o2 ? b2_ : r0; D3 = o2 ? b3_ : r1;
        }
        // 6. gates (i,f,g,o) and cell update; pack hcol pairs via shfl_xor(4)
        c0 = sigmoidf_(C1 + bl0[1]) * c0 + sigmoidf_(C0 + bl0[0]) * tanhf_(C2 + bl0[2]);
        c1 = sigmoidf_(D1 + bl1[1]) * c1 + sigmoidf_(D0 + bl1[0]) * tanhf_(D2 + bl1[2]);
        float h0 = sigmoidf_(C3 + bl0[3]) * tanhf_(c0);
        float h1 = sigmoidf_(D3 + bl1[3]) * tanhf_(c1);
        uint32_t hu0 = f2bf(h0), hu1 = f2bf(h1);
        uint32_t p0 = (uint32_t)__shfl_xor((int)hu0, 4);
        uint32_t p1 = (uint32_t)__shfl_xor((int)hu1, 4);
        uint32_t word = (a_ & 1) ? (p1 | (hu1 << 16)) : (hu0 | (p0 << 16));
        uint32_t* wp = ring + (t & 3) * RING_SLOT_W + (rowg + row) * 256 + colw;
        asm volatile("global_store_dword %0, %1, off sc0 sc1" :: "v"(wp), "v"(word) : "memory");
        hs32[((long)t * BATCH + rowg + row) * 256 + colw] = word;   // for heads (cached)
        // 7. per-wave signal: drain own stores, lane 0 stores this wave's flag
        asm volatile("s_waitcnt vmcnt(0)" ::: "memory");
        if (lane == 0) {
            uint32_t one = 1;
            const uint32_t* fq = flags + ((long)g * T_STEPS + t) * 64 + slice * 4 + wave;
            asm volatile("global_store_dword %0, %1, off sc0 sc1" :: "v"(fq), "v"(one) : "memory");
        }
    }
}

// ---------------- Heads: mu/sigma/value from hs (separate dispatch) ----------------
__global__ __launch_bounds__(256) void heads_kernel(
    const unsigned short* __restrict__ hs, const float* __restrict__ W_mu,
    const float* __restrict__ b_mu, const float* __restrict__ log_std,
    const float* __restrict__ W_v, const float* __restrict__ b_v,
    float* __restrict__ mu_out, float* __restrict__ sig_out,
    float* __restrict__ val_out) {
    __shared__ unsigned short wlds[32 * HSZ];     // [n=32][k=512]: 0-15 mu, 16 v, rest 0
    int tid = threadIdx.x;
    for (int idx = tid; idx < 32 * HSZ; idx += 256) {
        int n = idx & 31, k = idx >> 5;
        float w = 0.f;
        if (n < 16) w = W_mu[k * 16 + n];
        else if (n == 16) w = W_v[k];
        int byte = ((n * HSZ + k) * 2) ^ ((n & 7) << 4);
        *(unsigned short*)((char*)wlds + byte) = f2bf(w);
    }
    __syncthreads();
    int wave = tid >> 6, lane = tid & 63;
    long m0 = (long)blockIdx.x * 64 + wave * 16;
    int arow = lane & 15, kq = lane >> 4;
    f32x4 acc0 = {0.f, 0.f, 0.f, 0.f}, acc1 = {0.f, 0.f, 0.f, 0.f};
    const unsigned short* hr = hs + (m0 + arow) * HSZ + kq * 8;
#pragma unroll
    for (int kk = 0; kk < HSZ; kk += 32) {
        short8 af = *(const short8*)(hr + kk);
        int n0 = arow;
        int b0 = ((n0 * HSZ + kk + kq * 8) * 2) ^ ((n0 & 7) << 4);
        short8 bf0 = *(const short8*)((char*)wlds + b0);
        acc0 = __builtin_amdgcn_mfma_f32_16x16x32_bf16(af, bf0, acc0, 0, 0, 0);
        int n1 = 16 + arow;
        int b1 = ((n1 * HSZ + kk + kq * 8) * 2) ^ ((n1 & 7) << 4);
        short8 bf1 = *(const short8*)((char*)wlds + b1);
        acc1 = __builtin_amdgcn_mfma_f32_16x16x32_bf16(af, bf1, acc1, 0, 0, 0);
    }
    int col = lane & 15;
    float bm = b_mu[col];
    float sg = __expf(log_std[col]);
#pragma unroll
    for (int j = 0; j < 4; j++) {
        long row = m0 + kq * 4 + j;
        mu_out[row * 16 + col]  = acc0[j] + bm;
        sig_out[row * 16 + col] = sg;
    }
    if (col == 0) {
        float bv = b_v[0];
#pragma unroll
        for (int j = 0; j < 4; j++) {
            long row = m0 + kq * 4 + j;
            val_out[row] = acc1[j] + bv;
        }
    }
}

extern "C" void kernel_launch(void* const* d_in, const int* in_sizes, int n_in,
                              void* d_out, int out_size, void* d_ws, size_t ws_size,
                              hipStream_t stream) {
    const float* x      = (const float*)d_in[0];
    const float* W_enc  = (const float*)d_in[1];
    const float* b_enc  = (const float*)d_in[2];
    const float* Wi     = (const float*)d_in[3];
    const float* Wh     = (const float*)d_in[4];
    const float* b_lstm = (const float*)d_in[5];
    const float* W_mu   = (const float*)d_in[6];
    const float* b_mu   = (const float*)d_in[7];
    const float* lstd   = (const float*)d_in[8];
    const float* W_v    = (const float*)d_in[9];
    const float* b_v    = (const float*)d_in[10];

    char* ws = (char*)d_ws;
    uint32_t*       ring  = (uint32_t*)ws;                            // 1MB ring (4 slots)
    uint32_t*       flags = (uint32_t*)(ws + (1 << 20));              // 1MB per-wave flags
    unsigned short* Wipk  = (unsigned short*)(ws + (2 << 20));        // 1MB packed Wi
    unsigned short* Whpk  = (unsigned short*)(ws + (3 << 20));        // 1MB packed Wh b0-half
    unsigned short* feats = (unsigned short*)(ws + (4 << 20));        // 33.6MB bf16
    unsigned short* hs    = (unsigned short*)(ws + (4 << 20) + 33554432); // 67.1MB
    // total ws use: ~105MB

    float* mu_out  = (float*)d_out;                 // (T*B,16) f32
    float* sig_out = mu_out + 1048576;              // (T*B,16) f32
    float* val_out = mu_out + 2097152;              // (T*B,)   f32

    hipMemsetAsync(flags, 0, (size_t)NG * T_STEPS * 64 * sizeof(uint32_t), stream);
    prep_wi<<<dim3(256), dim3(256), 0, stream>>>(Wi, Wipk);
    prep_wh<<<dim3(256), dim3(256), 0, stream>>>(Wh, Whpk);
    enc_kernel<<<dim3(1024), dim3(256), 0, stream>>>(x, W_enc, b_enc, feats);
    scan_kernel<<<dim3(256), dim3(256), 0, stream>>>(b_lstm, feats, Wipk, Whpk, Wh,
                                                     ring, flags, (uint32_t*)hs);
    heads_kernel<<<dim3(1024), dim3(256), 0, stream>>>(hs, W_mu, b_mu, lstd, W_v, b_v,
                                                       mu_out, sig_out, val_out);
}

// Round 11
// 889.445 us; speedup vs baseline: 1.6312x; 1.4942x over previous
//
#include <hip/hip_runtime.h>
#include <stdint.h>

#define T_STEPS 256
#define BATCH   256
#define OBS     128
#define HID     256
#define HSZ     512
#define NG      16          // batch groups
#define RPG     16          // batch rows per group
#define NSLICES 16          // h-col slices per group
#define HCS     32          // h-cols per slice
#define RING_SLOT_W 65536   // u32 words per ring slot: 256 rows x 256 word-cols

typedef __attribute__((ext_vector_type(8))) short short8;
typedef __attribute__((ext_vector_type(4))) float f32x4;
typedef __attribute__((ext_vector_type(4))) int   i32x4;

__device__ __forceinline__ unsigned short f2bf(float x) {
    union { float f; uint32_t u; } v; v.f = x;
    uint32_t r = v.u + 0x7FFF + ((v.u >> 16) & 1);
    return (unsigned short)(r >> 16);
}
__device__ __forceinline__ float sigmoidf_(float x) { return 1.f / (1.f + __expf(-x)); }
__device__ __forceinline__ float tanhf_(float x)    { return 1.f - 2.f / (1.f + __expf(2.f * x)); }

// ---------------- Encoder: feats = gelu(x @ W_enc + b_enc), bf16 out ----------------
__global__ __launch_bounds__(256) void enc_kernel(
    const float* __restrict__ x, const float* __restrict__ W_enc,
    const float* __restrict__ b_enc, unsigned short* __restrict__ feats) {
    __shared__ unsigned short wlds[HID * OBS];   // [n=256][k=128] bf16 swizzled, 64KB
    int tid = threadIdx.x;
    for (int idx = tid; idx < OBS * HID; idx += 256) {
        int k = idx >> 8, n = idx & 255;
        int byte = ((n * OBS + k) * 2) ^ ((n & 7) << 4);
        *(unsigned short*)((char*)wlds + byte) = f2bf(W_enc[k * HID + n]);
    }
    __syncthreads();
    int wave = tid >> 6, lane = tid & 63;
    long m0 = (long)blockIdx.x * 64 + wave * 16;
    int arow = lane & 15, kq = lane >> 4;
    f32x4 acc[16];
    f32x4 z4 = {0.f, 0.f, 0.f, 0.f};
#pragma unroll
    for (int i = 0; i < 16; i++) acc[i] = z4;
#pragma unroll
    for (int kk = 0; kk < OBS; kk += 32) {
        const float* ap = x + (m0 + arow) * OBS + kk + kq * 8;
        float4 a0 = *(const float4*)ap;
        float4 a1 = *(const float4*)(ap + 4);
        short8 af;
        af[0] = (short)f2bf(a0.x); af[1] = (short)f2bf(a0.y);
        af[2] = (short)f2bf(a0.z); af[3] = (short)f2bf(a0.w);
        af[4] = (short)f2bf(a1.x); af[5] = (short)f2bf(a1.y);
        af[6] = (short)f2bf(a1.z); af[7] = (short)f2bf(a1.w);
#pragma unroll
        for (int nt = 0; nt < 16; nt++) {
            int n = nt * 16 + arow;
            int byte = ((n * OBS + kk + kq * 8) * 2) ^ ((n & 7) << 4);
            short8 bf = *(const short8*)((char*)wlds + byte);
            acc[nt] = __builtin_amdgcn_mfma_f32_16x16x32_bf16(af, bf, acc[nt], 0, 0, 0);
        }
    }
#pragma unroll
    for (int nt = 0; nt < 16; nt++) {
        int col = nt * 16 + (lane & 15);
        float bias = b_enc[col];
#pragma unroll
        for (int j = 0; j < 4; j++) {
            long row = m0 + kq * 4 + j;
            float z = acc[nt][j] + bias;
            float zc = 0.79788456f * (z + 0.044715f * z * z * z);
            float g = 0.5f * z * (1.f + tanhf_(zc));
            feats[row * HID + col] = f2bf(g);
        }
    }
}

// ---------------- Prep: Wi fragments, per-lane layout ----------------
__global__ __launch_bounds__(256) void prep_wi(
    const float* __restrict__ Wi, unsigned short* __restrict__ Wipk) {
    int t = blockIdx.x * 256 + threadIdx.x;        // 65536 threads
    int f = t & 15, l = (t >> 4) & 63, w = (t >> 10) & 3, s = t >> 12;
    int ct = f >> 3, i = f & 7;
    int n = w * 32 + ct * 16 + (l & 15);
    int colg = (n & 3) * HSZ + s * HCS + (n >> 2);
    int kbase = i * 32 + (l >> 4) * 8;
    short8 v;
#pragma unroll
    for (int j = 0; j < 8; j++) v[j] = (short)f2bf(Wi[(kbase + j) * 2048 + colg]);
    *(short8*)(Wipk + (long)t * 8) = v;
}

// ---------------- Prep: swizzled per-slice LDS image of Wh (2MB) ----------------
// image[s] byte P = (n*1024 + k*2) ^ ((n&7)<<4) holds bf16(Wh[k*2048 + colg(n,s)])
__global__ __launch_bounds__(256) void prep_whimg(
    const float* __restrict__ Wh, unsigned short* __restrict__ WhImg) {
    int t = blockIdx.x * 256 + threadIdx.x;        // 524288 threads
    int s = t >> 15, r = t & 32767;
    int n = r >> 8, k2 = (r & 255) * 2;
    int colg = (n & 3) * HSZ + s * HCS + (n >> 2);
    unsigned short a = f2bf(Wh[k2 * 2048 + colg]);
    unsigned short b = f2bf(Wh[(k2 + 1) * 2048 + colg]);
    uint32_t w = (uint32_t)a | ((uint32_t)b << 16);
    int P = (n * 1024 + k2 * 2) ^ ((n & 7) << 4);
    *(uint32_t*)((char*)WhImg + s * 131072 + P) = w;
}

// ---------------- Persistent LSTM scan (16 per-WG flags, 2 barriers/step) ----------------
// 256 WGs = 16 groups x 16 slices; LDS 144KB -> 1 WG/CU, all resident.
__global__ __launch_bounds__(256, 1) void scan_kernel(
    const float* __restrict__ b_lstm, const unsigned short* __restrict__ feats,
    const unsigned short* __restrict__ Wipk, const unsigned short* __restrict__ WhImg,
    uint32_t* __restrict__ ring, uint32_t* __restrict__ flags,
    uint32_t* __restrict__ hs32) {
    __shared__ unsigned short whs[128 * HSZ];     // full Wh slice, swizzled image, 128KB
    __shared__ unsigned short hst[RPG * HSZ];     // staged h [16][512] swizzled, 16KB
    const int tid = threadIdx.x;
    const int g = blockIdx.x & 15;
    const int slice = blockIdx.x >> 4;
    const int rowg = g * RPG;
    const int wave = tid >> 6, lane = tid & 63;
    const int arow = lane & 15, kq = lane >> 4;

    // 1. copy pre-swizzled Wh image into LDS (coalesced 16B)
    {
        const i32x4* src = (const i32x4*)((const char*)WhImg + slice * 131072);
        i32x4* dst = (i32x4*)whs;
        for (int idx = tid; idx < 8192; idx += 256) dst[idx] = src[idx];
    }
    // 2. Wi fragments -> registers (64 VGPR; no other reg-resident weights)
    short8 wif0[8], wif1[8];
    {
        const short8* wp = (const short8*)Wipk + ((slice * 4 + wave) * 64 + lane) * 16;
#pragma unroll
        for (int i = 0; i < 8; i++) { wif0[i] = wp[i]; wif1[i] = wp[8 + i]; }
    }
    // per-lane gate ownership after transpose (proven in R9/R10)
    const int a_ = arow >> 2;
    const int hcol0 = slice * HCS + wave * 8 + a_;
    float bl0[4], bl1[4];
#pragma unroll
    for (int q = 0; q < 4; q++) {
        bl0[q] = b_lstm[q * HSZ + hcol0];
        bl1[q] = b_lstm[q * HSZ + hcol0 + 4];
    }
    const int row = kq * 4 + (arow & 3);
    const int colw = slice * 16 + wave * 4 + ((a_ & 1) ? 2 + (a_ >> 1) : (a_ >> 1));
    float c0 = 0.f, c1 = 0.f;
    // stage ownership: lane l of wave w loads global rows {j*4+w}, bytes l*16 (coalesced);
    // LDS writes lane-contiguous b128 (conflict-free), same content map as A-reads expect
    int wb[4];
#pragma unroll
    for (int j = 0; j < 4; j++) {
        int rj = j * 4 + wave;
        wb[j] = (rj * 1024 + lane * 16) ^ ((rj & 7) << 4);
    }
    // feats prefetch for t=0
    short8 ff[8];
    {
        const char* fb = (const char*)feats + ((long)(rowg + arow)) * (HID * 2) + kq * 16;
#pragma unroll
        for (int i = 0; i < 8; i++) ff[i] = *(const short8*)(fb + i * 64);
    }
    f32x4 z4 = {0.f, 0.f, 0.f, 0.f};
    __syncthreads();

    for (int t = 0; t < T_STEPS; ++t) {
        // x-gates: pure register MFMA
        f32x4 acc0 = z4, acc1 = z4;
#pragma unroll
        for (int i = 0; i < 8; i++) {
            acc0 = __builtin_amdgcn_mfma_f32_16x16x32_bf16(ff[i], wif0[i], acc0, 0, 0, 0);
            acc1 = __builtin_amdgcn_mfma_f32_16x16x32_bf16(ff[i], wif1[i], acc1, 0, 0, 0);
        }
        // prefetch feats for t+1 (hides under poll)
        {
            int tn = (t + 1 < T_STEPS) ? t + 1 : t;
            const char* fb = (const char*)feats
                           + ((long)tn * BATCH + rowg + arow) * (HID * 2) + kq * 16;
#pragma unroll
            for (int i = 0; i < 8; i++) ff[i] = *(const short8*)(fb + i * 64);
        }
        __builtin_amdgcn_sched_barrier(0);
        if (t > 0) {
            // poll 16 per-WG flags, all 4 waves independently (one 64B line)
            const uint32_t* fp = flags + ((long)g * T_STEPS + t - 1) * 16 + (lane & 15);
            while (!__all(__hip_atomic_load(fp, __ATOMIC_RELAXED,
                                            __HIP_MEMORY_SCOPE_AGENT) != 0u)) {}
            __builtin_amdgcn_sched_barrier(0);
            // stage h(t-1): 4 coherent coalesced 16B loads per lane
            const char* rb = (const char*)ring + ((t - 1) & 3) * (RING_SLOT_W * 4)
                           + (rowg + wave) * 1024 + lane * 16;
            i32x4 S0, S1, S2, S3;
            asm volatile(
                "global_load_dwordx4 %0, %4, off sc0 sc1\n\t"
                "global_load_dwordx4 %1, %5, off sc0 sc1\n\t"
                "global_load_dwordx4 %2, %6, off sc0 sc1\n\t"
                "global_load_dwordx4 %3, %7, off sc0 sc1"
                : "=&v"(S0), "=&v"(S1), "=&v"(S2), "=&v"(S3)
                : "v"(rb), "v"(rb + 4096), "v"(rb + 8192), "v"(rb + 12288));
            asm volatile("s_waitcnt vmcnt(0)" ::: "memory");
            __builtin_amdgcn_sched_barrier(0);
            *(i32x4*)((char*)hst + wb[0]) = S0;
            *(i32x4*)((char*)hst + wb[1]) = S1;
            *(i32x4*)((char*)hst + wb[2]) = S2;
            *(i32x4*)((char*)hst + wb[3]) = S3;
            __syncthreads();                      // stage-ready
            // recurrent MFMAs: A from staged h, B from whs (both LDS, conflict-free)
            const int n0 = wave * 32 + arow, n1 = n0 + 16;
#pragma unroll
            for (int i = 0; i < 16; i++) {
                short8 ah = *(const short8*)((char*)hst
                              + ((arow * 1024 + i * 64 + kq * 16) ^ ((arow & 7) << 4)));
                short8 b0 = *(const short8*)((char*)whs
                              + ((n0 * 1024 + i * 64 + kq * 16) ^ ((n0 & 7) << 4)));
                short8 b1 = *(const short8*)((char*)whs
                              + ((n1 * 1024 + i * 64 + kq * 16) ^ ((n1 & 7) << 4)));
                acc0 = __builtin_amdgcn_mfma_f32_16x16x32_bf16(ah, b0, acc0, 0, 0, 0);
                acc1 = __builtin_amdgcn_mfma_f32_16x16x32_bf16(ah, b1, acc1, 0, 0, 0);
            }
        }
        // 4x4 in-cluster transpose -> lane-local (i,f,g,o)  [proven R9/R10]
        float C0, C1, C2, C3, D0, D1, D2, D3;
        {
            float s0 = __shfl_xor(acc0[0], 1), s1 = __shfl_xor(acc0[1], 1);
            float s2 = __shfl_xor(acc0[2], 1), s3 = __shfl_xor(acc0[3], 1);
            bool o1 = arow & 1;
            float b0_ = o1 ? s1 : acc0[0], b1_ = o1 ? acc0[1] : s0;
            float b2_ = o1 ? s3 : acc0[2], b3_ = o1 ? acc0[3] : s2;
            float r0 = __shfl_xor(b0_, 2), r1 = __shfl_xor(b1_, 2);
            float r2 = __shfl_xor(b2_, 2), r3 = __shfl_xor(b3_, 2);
            bool o2 = arow & 2;
            C0 = o2 ? r2 : b0_; C1 = o2 ? r3 : b1_;
            C2 = o2 ? b2_ : r0; C3 = o2 ? b3_ : r1;
            s0 = __shfl_xor(acc1[0], 1); s1 = __shfl_xor(acc1[1], 1);
            s2 = __shfl_xor(acc1[2], 1); s3 = __shfl_xor(acc1[3], 1);
            b0_ = o1 ? s1 : acc1[0]; b1_ = o1 ? acc1[1] : s0;
            b2_ = o1 ? s3 : acc1[2]; b3_ = o1 ? acc1[3] : s2;
            r0 = __shfl_xor(b0_, 2); r1 = __shfl_xor(b1_, 2);
            r2 = __shfl_xor(b2_, 2); r3 = __shfl_xor(b3_, 2);
            D0 = o2 ? r2 : b0_; D1 = o2 ? r3 : b1_;
            D2 = o2 ? b2_ : r0; D3 = o2 ? b3_ : r1;
        }
        // gates + cell update; pack hcol pairs via shfl_xor(4)
        c0 = sigmoidf_(C1 + bl0[1]) * c0 + sigmoidf_(C0 + bl0[0]) * tanhf_(C2 + bl0[2]);
        c1 = sigmoidf_(D1 + bl1[1]) * c1 + sigmoidf_(D0 + bl1[0]) * tanhf_(D2 + bl1[2]);
        float h0 = sigmoidf_(C3 + bl0[3]) * tanhf_(c0);
        float h1 = sigmoidf_(D3 + bl1[3]) * tanhf_(c1);
        uint32_t hu0 = f2bf(h0), hu1 = f2bf(h1);
        uint32_t p0 = (uint32_t)__shfl_xor((int)hu0, 4);
        uint32_t p1 = (uint32_t)__shfl_xor((int)hu1, 4);
        uint32_t word = (a_ & 1) ? (p1 | (hu1 << 16)) : (hu0 | (p0 << 16));
        uint32_t* wp = ring + (t & 3) * RING_SLOT_W + (rowg + row) * 256 + colw;
        asm volatile("global_store_dword %0, %1, off sc0 sc1" :: "v"(wp), "v"(word) : "memory");
        hs32[((long)t * BATCH + rowg + row) * 256 + colw] = word;   // for heads (cached)
        __syncthreads();            // drains each wave's vmcnt before s_barrier
        if (tid == 0) {
            uint32_t one = 1;
            const uint32_t* fq = flags + ((long)g * T_STEPS + t) * 16 + slice;
            asm volatile("global_store_dword %0, %1, off sc0 sc1" :: "v"(fq), "v"(one) : "memory");
        }
    }
}

// ---------------- Heads: mu/sigma/value from hs (separate dispatch) ----------------
__global__ __launch_bounds__(256) void heads_kernel(
    const unsigned short* __restrict__ hs, const float* __restrict__ W_mu,
    const float* __restrict__ b_mu, const float* __restrict__ log_std,
    const float* __restrict__ W_v, const float* __restrict__ b_v,
    float* __restrict__ mu_out, float* __restrict__ sig_out,
    float* __restrict__ val_out) {
    __shared__ unsigned short wlds[32 * HSZ];     // [n=32][k=512]: 0-15 mu, 16 v, rest 0
    int tid = threadIdx.x;
    for (int idx = tid; idx < 32 * HSZ; idx += 256) {
        int n = idx & 31, k = idx >> 5;
        float w = 0.f;
        if (n < 16) w = W_mu[k * 16 + n];
        else if (n == 16) w = W_v[k];
        int byte = ((n * HSZ + k) * 2) ^ ((n & 7) << 4);
        *(unsigned short*)((char*)wlds + byte) = f2bf(w);
    }
    __syncthreads();
    int wave = tid >> 6, lane = tid & 63;
    long m0 = (long)blockIdx.x * 64 + wave * 16;
    int arow = lane & 15, kq = lane >> 4;
    f32x4 acc0 = {0.f, 0.f, 0.f, 0.f}, acc1 = {0.f, 0.f, 0.f, 0.f};
    const unsigned short* hr = hs + (m0 + arow) * HSZ + kq * 8;
#pragma unroll
    for (int kk = 0; kk < HSZ; kk += 32) {
        short8 af = *(const short8*)(hr + kk);
        int n0 = arow;
        int b0 = ((n0 * HSZ + kk + kq * 8) * 2) ^ ((n0 & 7) << 4);
        short8 bf0 = *(const short8*)((char*)wlds + b0);
        acc0 = __builtin_amdgcn_mfma_f32_16x16x32_bf16(af, bf0, acc0, 0, 0, 0);
        int n1 = 16 + arow;
        int b1 = ((n1 * HSZ + kk + kq * 8) * 2) ^ ((n1 & 7) << 4);
        short8 bf1 = *(const short8*)((char*)wlds + b1);
        acc1 = __builtin_amdgcn_mfma_f32_16x16x32_bf16(af, bf1, acc1, 0, 0, 0);
    }
    int col = lane & 15;
    float bm = b_mu[col];
    float sg = __expf(log_std[col]);
#pragma unroll
    for (int j = 0; j < 4; j++) {
        long row = m0 + kq * 4 + j;
        mu_out[row * 16 + col]  = acc0[j] + bm;
        sig_out[row * 16 + col] = sg;
    }
    if (col == 0) {
        float bv = b_v[0];
#pragma unroll
        for (int j = 0; j < 4; j++) {
            long row = m0 + kq * 4 + j;
            val_out[row] = acc1[j] + bv;
        }
    }
}

extern "C" void kernel_launch(void* const* d_in, const int* in_sizes, int n_in,
                              void* d_out, int out_size, void* d_ws, size_t ws_size,
                              hipStream_t stream) {
    const float* x      = (const float*)d_in[0];
    const float* W_enc  = (const float*)d_in[1];
    const float* b_enc  = (const float*)d_in[2];
    const float* Wi     = (const float*)d_in[3];
    const float* Wh     = (const float*)d_in[4];
    const float* b_lstm = (const float*)d_in[5];
    const float* W_mu   = (const float*)d_in[6];
    const float* b_mu   = (const float*)d_in[7];
    const float* lstd   = (const float*)d_in[8];
    const float* W_v    = (const float*)d_in[9];
    const float* b_v    = (const float*)d_in[10];

    char* ws = (char*)d_ws;
    uint32_t*       ring  = (uint32_t*)ws;                            // 1MB ring (4 slots)
    uint32_t*       flags = (uint32_t*)(ws + (1 << 20));              // 256KB per-WG flags
    unsigned short* Wipk  = (unsigned short*)(ws + (2 << 20));        // 1MB packed Wi frags
    unsigned short* WhImg = (unsigned short*)(ws + (3 << 20));        // 2MB swizzled Wh images
    unsigned short* feats = (unsigned short*)(ws + (5 << 20));        // 33.6MB bf16
    unsigned short* hs    = (unsigned short*)(ws + (5 << 20) + 33554432); // 67.1MB
    // total ws use: ~106MB

    float* mu_out  = (float*)d_out;                 // (T*B,16) f32
    float* sig_out = mu_out + 1048576;              // (T*B,16) f32
    float* val_out = mu_out + 2097152;              // (T*B,)   f32

    hipMemsetAsync(flags, 0, (size_t)NG * T_STEPS * 16 * sizeof(uint32_t), stream);
    prep_wi<<<dim3(256), dim3(256), 0, stream>>>(Wi, Wipk);
    prep_whimg<<<dim3(2048), dim3(256), 0, stream>>>(Wh, WhImg);
    enc_kernel<<<dim3(1024), dim3(256), 0, stream>>>(x, W_enc, b_enc, feats);
    scan_kernel<<<dim3(256), dim3(256), 0, stream>>>(b_lstm, feats, Wipk, WhImg,
                                                     ring, flags, (uint32_t*)hs);
    heads_kernel<<<dim3(1024), dim3(256), 0, stream>>>(hs, W_mu, b_mu, lstd, W_v, b_v,
                                                       mu_out, sig_out, val_out);
}